// Round 1
// baseline (2336.844 us; speedup 1.0000x reference)
//
#include <hip/hip_runtime.h>

#define H 192
#define NL 5
#define NN 60000
#define NE 120000
#define NG 2048
#define ND 200
#define LDA 392  // 384 + 8 bf16 pad -> 784B row stride, 2-way bank alias (free)

typedef __bf16 bfrag __attribute__((ext_vector_type(8)));
typedef float f32x4 __attribute__((ext_vector_type(4)));

__device__ __forceinline__ unsigned short f2bf(float f) {
  union { float f; unsigned u; } v; v.f = f;
  return (unsigned short)((v.u + 0x7FFFu + ((v.u >> 16) & 1u)) >> 16);
}
__device__ __forceinline__ float gelu(float x) {
  return 0.5f * x * (1.0f + erff(x * 0.70710678118654752f));
}
__device__ __forceinline__ unsigned fenc(float f) {
  union { float f; unsigned u; } v; v.f = f;
  return (v.u & 0x80000000u) ? ~v.u : (v.u | 0x80000000u);
}
__device__ __forceinline__ float fdec(unsigned u) {
  union { float f; unsigned u; } v;
  v.u = (u & 0x80000000u) ? (u ^ 0x80000000u) : ~u;
  return v.f;
}

// ---------------- weight prep: transpose + bf16 ----------------
__global__ __launch_bounds__(256) void prep_kernel(
    const float* __restrict__ msg_w1, const float* __restrict__ msg_w2,
    const float* __restrict__ upd_w, const float* __restrict__ h1_w,
    const float* __restrict__ h2_w, const float* __restrict__ h3_w,
    unsigned short* __restrict__ W1t, float* __restrict__ w1last,
    unsigned short* __restrict__ W2t, unsigned short* __restrict__ Ut,
    float* __restrict__ h1t, float* __restrict__ h2t, float* __restrict__ h3t) {
  int idx = blockIdx.x * 256 + threadIdx.x;
  const int S1 = NL * 384 * 384;
  const int S2 = NL * 384;
  const int S3 = NL * 192 * 384;
  if (idx < S1) {
    int l = idx / (384 * 384); int r = idx % (384 * 384);
    int j = r / 384, k = r % 384;
    W1t[idx] = f2bf(msg_w1[(size_t)l * 385 * 384 + (size_t)k * 384 + j]);
    return;
  }
  idx -= S1;
  if (idx < S2) {
    int l = idx / 384, j = idx % 384;
    w1last[idx] = msg_w1[(size_t)l * 385 * 384 + 384 * 384 + j];
    return;
  }
  idx -= S2;
  if (idx < S3) {
    int l = idx / (192 * 384); int r = idx % (192 * 384);
    int j = r / 384, k = r % 384;
    W2t[idx] = f2bf(msg_w2[(size_t)l * 384 * 192 + (size_t)k * 192 + j]);
    return;
  }
  idx -= S3;
  if (idx < S3) {
    int l = idx / (192 * 384); int r = idx % (192 * 384);
    int j = r / 384, k = r % 384;
    Ut[idx] = f2bf(upd_w[(size_t)l * 384 * 192 + (size_t)k * 192 + j]);
    return;
  }
  idx -= S3;
  if (idx < 192 * 384) { int j = idx / 384, k = idx % 384; h1t[idx] = h1_w[k * 192 + j]; return; }
  idx -= 192 * 384;
  if (idx < 96 * 192) { int j = idx / 192, k = idx % 192; h2t[idx] = h2_w[k * 96 + j]; return; }
  idx -= 96 * 192;
  if (idx < 200 * 96) { int j = idx / 96, k = idx % 96; h3t[idx] = h3_w[k * 200 + j]; return; }
}

// ---------------- encoder: x = LN(GELU(af @ W + b)) ----------------
__global__ __launch_bounds__(256) void enc_kernel(
    const float* __restrict__ af, const float* __restrict__ w,
    const float* __restrict__ b, const float* __restrict__ g,
    const float* __restrict__ bb, float* __restrict__ x) {
  const int node = blockIdx.x * 4 + (threadIdx.x >> 6);
  const int lane = threadIdx.x & 63;
  if (node >= NN) return;
  const float a0 = af[node * 4 + 0], a1 = af[node * 4 + 1];
  const float a2 = af[node * 4 + 2], a3 = af[node * 4 + 3];
  float v[3], s = 0.f, ss = 0.f;
#pragma unroll
  for (int i = 0; i < 3; ++i) {
    const int j = lane + i * 64;
    float o = a0 * w[j] + a1 * w[H + j] + a2 * w[2 * H + j] + a3 * w[3 * H + j] + b[j];
    o = gelu(o);
    v[i] = o; s += o; ss += o * o;
  }
#pragma unroll
  for (int m = 1; m < 64; m <<= 1) { s += __shfl_xor(s, m); ss += __shfl_xor(ss, m); }
  const float mu = s * (1.f / H);
  float var = ss * (1.f / H) - mu * mu;
  const float rstd = rsqrtf(fmaxf(var, 0.f) + 1e-5f);
#pragma unroll
  for (int i = 0; i < 3; ++i) {
    const int j = lane + i * 64;
    x[(size_t)node * H + j] = (v[i] - mu) * rstd * g[j] + bb[j];
  }
}

// ---------------- fused message MLP + scatter-add ----------------
// 64 edges/block, 4 waves. GEMM1: hidden[64x384]=GELU(A@W1+b1+ea*w1last) (wave: 64x96)
// GEMM2: m[64x192]=hidden@W2+b2 (wave: 64x48) -> atomicAdd to agg[dst]
__global__ __launch_bounds__(256, 2) void msg_kernel(
    const float* __restrict__ x, const int* __restrict__ ei,
    const float* __restrict__ ea, const unsigned short* __restrict__ W1t,
    const float* __restrict__ w1last, const float* __restrict__ b1,
    const unsigned short* __restrict__ W2t, const float* __restrict__ b2,
    float* __restrict__ agg) {
  __shared__ unsigned short A[64 * LDA];
  __shared__ int dstS[64];
  __shared__ float eaS[64];
  const int tid = threadIdx.x;
  const int wave = tid >> 6, lane = tid & 63;
  const int lrow = lane & 15, kgrp = lane >> 4;
  const int tile = blockIdx.x * 64;

  if (tid < 64) {
    dstS[tid] = ei[NE + tile + tid];
    eaS[tid] = ea[tile + tid];
  }
  for (int r = wave; r < 64; r += 4) {
    const int e = tile + r;
    const float4* xs4 = (const float4*)(x + (size_t)ei[e] * H);
    const float4* xd4 = (const float4*)(x + (size_t)ei[NE + e] * H);
    for (int f = lane; f < 96; f += 64) {
      float4 v = (f < 48) ? xs4[f] : xd4[f - 48];
      ushort4 u = make_ushort4(f2bf(v.x), f2bf(v.y), f2bf(v.z), f2bf(v.w));
      *(ushort4*)(&A[r * LDA + f * 4]) = u;
    }
  }
  __syncthreads();

  const int jbase = wave * 96;
  f32x4 acc[4][6];
#pragma unroll
  for (int mf = 0; mf < 4; ++mf)
#pragma unroll
    for (int nf = 0; nf < 6; ++nf)
#pragma unroll
      for (int q = 0; q < 4; ++q) acc[mf][nf][q] = 0.f;

  for (int kk = 0; kk < 12; ++kk) {
    const int k0 = kk * 32 + kgrp * 8;
    bfrag aF[4];
#pragma unroll
    for (int mf = 0; mf < 4; ++mf)
      aF[mf] = *(const bfrag*)(&A[(lrow + 16 * mf) * LDA + k0]);
#pragma unroll
    for (int nf = 0; nf < 6; ++nf) {
      const bfrag bF = *(const bfrag*)(W1t + (size_t)(jbase + nf * 16 + lrow) * 384 + k0);
#pragma unroll
      for (int mf = 0; mf < 4; ++mf)
        acc[mf][nf] = __builtin_amdgcn_mfma_f32_16x16x32_bf16(aF[mf], bF, acc[mf][nf], 0, 0, 0);
    }
  }
  __syncthreads();  // all A reads done before overwrite

#pragma unroll
  for (int nf = 0; nf < 6; ++nf) {
    const int col = jbase + nf * 16 + lrow;
    const float bias = b1[col], wl = w1last[col];
#pragma unroll
    for (int mf = 0; mf < 4; ++mf) {
#pragma unroll
      for (int q = 0; q < 4; ++q) {
        const int row = 16 * mf + kgrp * 4 + q;
        const float h = acc[mf][nf][q] + bias + eaS[row] * wl;
        A[row * LDA + col] = f2bf(gelu(h));
      }
    }
  }
  __syncthreads();

  f32x4 acc2[4][3];
#pragma unroll
  for (int mf = 0; mf < 4; ++mf)
#pragma unroll
    for (int nf = 0; nf < 3; ++nf)
#pragma unroll
      for (int q = 0; q < 4; ++q) acc2[mf][nf][q] = 0.f;

  const int j2base = wave * 48;
  for (int kk = 0; kk < 12; ++kk) {
    const int k0 = kk * 32 + kgrp * 8;
    bfrag aF[4];
#pragma unroll
    for (int mf = 0; mf < 4; ++mf)
      aF[mf] = *(const bfrag*)(&A[(lrow + 16 * mf) * LDA + k0]);
#pragma unroll
    for (int nf = 0; nf < 3; ++nf) {
      const bfrag bF = *(const bfrag*)(W2t + (size_t)(j2base + nf * 16 + lrow) * 384 + k0);
#pragma unroll
      for (int mf = 0; mf < 4; ++mf)
        acc2[mf][nf] = __builtin_amdgcn_mfma_f32_16x16x32_bf16(aF[mf], bF, acc2[mf][nf], 0, 0, 0);
    }
  }
#pragma unroll
  for (int nf = 0; nf < 3; ++nf) {
    const int col = j2base + nf * 16 + lrow;
    const float bias = b2[col];
#pragma unroll
    for (int mf = 0; mf < 4; ++mf) {
#pragma unroll
      for (int q = 0; q < 4; ++q) {
        const int row = 16 * mf + kgrp * 4 + q;
        atomicAdd(&agg[(size_t)dstS[row] * H + col], acc2[mf][nf][q] + bias);
      }
    }
  }
}

// ---------------- update MLP + residual + LN (in-place on x) ----------------
// 64 nodes/block, wave w owns rows w*16..w*16+15 (1 m-frag x 12 n-frags)
__global__ __launch_bounds__(256, 2) void upd_kernel(
    const unsigned short* __restrict__ Ut, const float* __restrict__ ub,
    const float* __restrict__ lng, const float* __restrict__ lnb,
    const float* __restrict__ agg, float* __restrict__ x) {
  __shared__ unsigned short A[64 * LDA];
  const int tid = threadIdx.x;
  const int wave = tid >> 6, lane = tid & 63;
  const int lrow = lane & 15, kgrp = lane >> 4;
  const int tile = blockIdx.x * 64;

  for (int r = wave; r < 64; r += 4) {
    const int node = tile + r;
    if (node < NN) {
      const float4* xs4 = (const float4*)(x + (size_t)node * H);
      const float4* xa4 = (const float4*)(agg + (size_t)node * H);
      for (int f = lane; f < 96; f += 64) {
        float4 v = (f < 48) ? xs4[f] : xa4[f - 48];
        ushort4 u = make_ushort4(f2bf(v.x), f2bf(v.y), f2bf(v.z), f2bf(v.w));
        *(ushort4*)(&A[r * LDA + f * 4]) = u;
      }
    } else {
      for (int f = lane; f < 96; f += 64)
        *(ushort4*)(&A[r * LDA + f * 4]) = make_ushort4(0, 0, 0, 0);
    }
  }
  __syncthreads();

  f32x4 acc[12];
#pragma unroll
  for (int nf = 0; nf < 12; ++nf)
#pragma unroll
    for (int q = 0; q < 4; ++q) acc[nf][q] = 0.f;

  const int rowb = wave * 16;
  for (int kk = 0; kk < 12; ++kk) {
    const int k0 = kk * 32 + kgrp * 8;
    const bfrag aF = *(const bfrag*)(&A[(rowb + lrow) * LDA + k0]);
#pragma unroll
    for (int nf = 0; nf < 12; ++nf) {
      const bfrag bF = *(const bfrag*)(Ut + (size_t)(nf * 16 + lrow) * 384 + k0);
      acc[nf] = __builtin_amdgcn_mfma_f32_16x16x32_bf16(aF, bF, acc[nf], 0, 0, 0);
    }
  }

  float s[4] = {0.f, 0.f, 0.f, 0.f}, ss[4] = {0.f, 0.f, 0.f, 0.f};
#pragma unroll
  for (int nf = 0; nf < 12; ++nf) {
    const int col = nf * 16 + lrow;
    const float bias = ub[col];
#pragma unroll
    for (int q = 0; q < 4; ++q) {
      const int node = tile + rowb + kgrp * 4 + q;
      float v = 0.f;
      if (node < NN) v = x[(size_t)node * H + col] + gelu(acc[nf][q] + bias);
      acc[nf][q] = v;
      s[q] += v; ss[q] += v * v;
    }
  }
#pragma unroll
  for (int m = 1; m < 16; m <<= 1) {
#pragma unroll
    for (int q = 0; q < 4; ++q) {
      s[q] += __shfl_xor(s[q], m);
      ss[q] += __shfl_xor(ss[q], m);
    }
  }
  float mu[4], rstd[4];
#pragma unroll
  for (int q = 0; q < 4; ++q) {
    mu[q] = s[q] * (1.f / H);
    float var = ss[q] * (1.f / H) - mu[q] * mu[q];
    rstd[q] = rsqrtf(fmaxf(var, 0.f) + 1e-5f);
  }
#pragma unroll
  for (int nf = 0; nf < 12; ++nf) {
    const int col = nf * 16 + lrow;
    const float gg = lng[col], bb = lnb[col];
#pragma unroll
    for (int q = 0; q < 4; ++q) {
      const int node = tile + rowb + kgrp * 4 + q;
      if (node < NN)
        x[(size_t)node * H + col] = (acc[nf][q] - mu[q]) * rstd[q] * gg + bb;
    }
  }
}

// ---------------- pooling ----------------
__global__ __launch_bounds__(256) void pool_init(float* __restrict__ sum,
                                                 unsigned* __restrict__ maxb,
                                                 float* __restrict__ cnt) {
  const int i = blockIdx.x * 256 + threadIdx.x;
  if (i < NG * H) { sum[i] = 0.f; maxb[i] = 0x007FFFFFu; }  // enc(-inf)
  if (i < NG) cnt[i] = 0.f;
}

__global__ __launch_bounds__(256) void pool_scatter(
    const float* __restrict__ x, const int* __restrict__ batch,
    float* __restrict__ sum, unsigned* __restrict__ maxb, float* __restrict__ cnt) {
  const int node = blockIdx.x * 4 + (threadIdx.x >> 6);
  const int lane = threadIdx.x & 63;
  if (node >= NN) return;
  const int gid = batch[node];
#pragma unroll
  for (int i = 0; i < 3; ++i) {
    const int c = lane + i * 64;
    const float v = x[(size_t)node * H + c];
    atomicAdd(&sum[gid * H + c], v);
    atomicMax(&maxb[gid * H + c], fenc(v));
  }
  if (lane == 0) atomicAdd(&cnt[gid], 1.f);
}

// ---------------- head MLP ----------------
__global__ __launch_bounds__(256) void head_kernel(
    const float* __restrict__ sum, const unsigned* __restrict__ maxb,
    const float* __restrict__ cnt,
    const float* __restrict__ h1t, const float* __restrict__ h1b,
    const float* __restrict__ h2t, const float* __restrict__ h2b,
    const float* __restrict__ h3t, const float* __restrict__ h3b,
    float* __restrict__ out) {
  __shared__ float G[4][2 * H];
  __shared__ float Hs[4][H];
  __shared__ float H2s[4][96];
  const int w = threadIdx.x >> 6, lane = threadIdx.x & 63;
  const int gi = blockIdx.x * 4 + w;
  const float inv = 1.f / fmaxf(cnt[gi], 1.f);
#pragma unroll
  for (int i = 0; i < 3; ++i) {
    const int j = lane + i * 64;
    G[w][j] = sum[gi * H + j] * inv;
    G[w][H + j] = fdec(maxb[gi * H + j]);
  }
  __syncthreads();
#pragma unroll
  for (int i = 0; i < 3; ++i) {
    const int j = lane + i * 64;
    const float4* wr4 = (const float4*)(h1t + (size_t)j * 384);
    float s = h1b[j];
    for (int k4 = 0; k4 < 96; ++k4) {
      float4 ww = wr4[k4];
      s += G[w][k4 * 4 + 0] * ww.x + G[w][k4 * 4 + 1] * ww.y +
           G[w][k4 * 4 + 2] * ww.z + G[w][k4 * 4 + 3] * ww.w;
    }
    Hs[w][j] = gelu(s);
  }
  __syncthreads();
  for (int j = lane; j < 96; j += 64) {
    const float4* wr4 = (const float4*)(h2t + (size_t)j * 192);
    float s = h2b[j];
    for (int k4 = 0; k4 < 48; ++k4) {
      float4 ww = wr4[k4];
      s += Hs[w][k4 * 4 + 0] * ww.x + Hs[w][k4 * 4 + 1] * ww.y +
           Hs[w][k4 * 4 + 2] * ww.z + Hs[w][k4 * 4 + 3] * ww.w;
    }
    H2s[w][j] = gelu(s);
  }
  __syncthreads();
  for (int j = lane; j < 200; j += 64) {
    const float4* wr4 = (const float4*)(h3t + (size_t)j * 96);
    float s = h3b[j];
    for (int k4 = 0; k4 < 24; ++k4) {
      float4 ww = wr4[k4];
      s += H2s[w][k4 * 4 + 0] * ww.x + H2s[w][k4 * 4 + 1] * ww.y +
           H2s[w][k4 * 4 + 2] * ww.z + H2s[w][k4 * 4 + 3] * ww.w;
    }
    out[(size_t)gi * ND + j] = s;
  }
}

extern "C" void kernel_launch(void* const* d_in, const int* in_sizes, int n_in,
                              void* d_out, int out_size, void* d_ws, size_t ws_size,
                              hipStream_t stream) {
  const float* atom   = (const float*)d_in[0];
  const float* ea     = (const float*)d_in[1];
  const int*   ei     = (const int*)d_in[2];
  const int*   batch  = (const int*)d_in[3];
  const float* enc_w  = (const float*)d_in[4];
  const float* enc_b  = (const float*)d_in[5];
  const float* enc_lng= (const float*)d_in[6];
  const float* enc_lnb= (const float*)d_in[7];
  const float* msg_w1 = (const float*)d_in[8];
  const float* msg_b1 = (const float*)d_in[9];
  const float* msg_w2 = (const float*)d_in[10];
  const float* msg_b2 = (const float*)d_in[11];
  const float* upd_w  = (const float*)d_in[12];
  const float* upd_b  = (const float*)d_in[13];
  const float* ln_g   = (const float*)d_in[14];
  const float* ln_b   = (const float*)d_in[15];
  const float* h1_w   = (const float*)d_in[16];
  const float* h1_b   = (const float*)d_in[17];
  const float* h2_w   = (const float*)d_in[18];
  const float* h2_b   = (const float*)d_in[19];
  const float* h3_w   = (const float*)d_in[20];
  const float* h3_b   = (const float*)d_in[21];
  float* out = (float*)d_out;

  char* ws = (char*)d_ws;
  size_t off = 0;
  auto alloc = [&](size_t bytes) -> void* {
    void* p = ws + off;
    off = (off + bytes + 255) & ~(size_t)255;
    return p;
  };
  float* x            = (float*)alloc((size_t)NN * H * 4);
  float* agg          = (float*)alloc((size_t)NN * H * 4);
  unsigned short* W1t = (unsigned short*)alloc((size_t)NL * 384 * 384 * 2);
  float* w1last       = (float*)alloc((size_t)NL * 384 * 4);
  unsigned short* W2t = (unsigned short*)alloc((size_t)NL * 192 * 384 * 2);
  unsigned short* Ut  = (unsigned short*)alloc((size_t)NL * 192 * 384 * 2);
  float* h1t          = (float*)alloc((size_t)192 * 384 * 4);
  float* h2t          = (float*)alloc((size_t)96 * 192 * 4);
  float* h3t          = (float*)alloc((size_t)200 * 96 * 4);
  float* psum         = (float*)alloc((size_t)NG * H * 4);
  unsigned* pmax      = (unsigned*)alloc((size_t)NG * H * 4);
  float* pcnt         = (float*)alloc((size_t)NG * 4);

  // prep: 737280+1920+368640+368640+73728+18432+19200 = 1,587,840 work items
  prep_kernel<<<6203, 256, 0, stream>>>(msg_w1, msg_w2, upd_w, h1_w, h2_w, h3_w,
                                        W1t, w1last, W2t, Ut, h1t, h2t, h3t);
  enc_kernel<<<NN / 4, 256, 0, stream>>>(atom, enc_w, enc_b, enc_lng, enc_lnb, x);
  for (int l = 0; l < NL; ++l) {
    hipMemsetAsync(agg, 0, (size_t)NN * H * 4, stream);
    msg_kernel<<<NE / 64, 256, 0, stream>>>(
        x, ei, ea, W1t + (size_t)l * 384 * 384, w1last + l * 384,
        msg_b1 + l * 384, W2t + (size_t)l * 192 * 384, msg_b2 + l * 192, agg);
    upd_kernel<<<(NN + 63) / 64, 256, 0, stream>>>(
        Ut + (size_t)l * 192 * 384, upd_b + l * 192, ln_g + l * 192,
        ln_b + l * 192, agg, x);
  }
  pool_init<<<(NG * H) / 256, 256, 0, stream>>>(psum, pmax, pcnt);
  pool_scatter<<<NN / 4, 256, 0, stream>>>(x, batch, psum, pmax, pcnt);
  head_kernel<<<NG / 4, 256, 0, stream>>>(psum, pmax, pcnt, h1t, h1_b, h2t, h2_b,
                                          h3t, h3_b, out);
}

// Round 2
// 1710.040 us; speedup vs baseline: 1.3665x; 1.3665x over previous
//
#include <hip/hip_runtime.h>

#define H 192
#define NL 5
#define NN 60000
#define NE 120000
#define NG 2048
#define ND 200
#define LDA 392  // 384 + 8 bf16 pad

typedef __bf16 bfrag __attribute__((ext_vector_type(8)));
typedef float f32x4 __attribute__((ext_vector_type(4)));

__device__ __forceinline__ unsigned short f2bf(float f) {
  union { float f; unsigned u; } v; v.f = f;
  return (unsigned short)((v.u + 0x7FFFu + ((v.u >> 16) & 1u)) >> 16);
}
__device__ __forceinline__ float bflo(unsigned u) {
  union { unsigned u; float f; } v; v.u = u << 16; return v.f;
}
__device__ __forceinline__ float bfhi(unsigned u) {
  union { unsigned u; float f; } v; v.u = u & 0xffff0000u; return v.f;
}
// tanh-approx GELU: x * sigmoid(1.5957691x(1+0.044715x^2)*2) via exp2; |err| ~3e-4
__device__ __forceinline__ float gelu(float x) {
  const float xt = fminf(fmaxf(x, -8.f), 8.f);
  const float xx = xt * xt;
  const float t = exp2f(xt * (-2.3020922f - 0.10293942f * xx));
  return x * __frcp_rn(1.f + t);
}

// ---------------- weight prep: transpose + bf16 ----------------
__global__ __launch_bounds__(256) void prep_kernel(
    const float* __restrict__ msg_w1, const float* __restrict__ msg_w2,
    const float* __restrict__ upd_w, const float* __restrict__ h1_w,
    const float* __restrict__ h2_w, const float* __restrict__ h3_w,
    unsigned short* __restrict__ W1t, float* __restrict__ w1last,
    unsigned short* __restrict__ W2t, unsigned short* __restrict__ Ut,
    float* __restrict__ h1t, float* __restrict__ h2t, float* __restrict__ h3t) {
  int idx = blockIdx.x * 256 + threadIdx.x;
  const int S1 = NL * 384 * 384;
  const int S2 = NL * 384;
  const int S3 = NL * 192 * 384;
  if (idx < S1) {
    int l = idx / (384 * 384); int r = idx % (384 * 384);
    int j = r / 384, k = r % 384;
    W1t[idx] = f2bf(msg_w1[(size_t)l * 385 * 384 + (size_t)k * 384 + j]);
    return;
  }
  idx -= S1;
  if (idx < S2) {
    int l = idx / 384, j = idx % 384;
    w1last[idx] = msg_w1[(size_t)l * 385 * 384 + 384 * 384 + j];
    return;
  }
  idx -= S2;
  if (idx < S3) {
    int l = idx / (192 * 384); int r = idx % (192 * 384);
    int j = r / 384, k = r % 384;
    W2t[idx] = f2bf(msg_w2[(size_t)l * 384 * 192 + (size_t)k * 192 + j]);
    return;
  }
  idx -= S3;
  if (idx < S3) {
    int l = idx / (192 * 384); int r = idx % (192 * 384);
    int j = r / 384, k = r % 384;
    Ut[idx] = f2bf(upd_w[(size_t)l * 384 * 192 + (size_t)k * 192 + j]);
    return;
  }
  idx -= S3;
  if (idx < 192 * 384) { int j = idx / 384, k = idx % 384; h1t[idx] = h1_w[k * 192 + j]; return; }
  idx -= 192 * 384;
  if (idx < 96 * 192) { int j = idx / 192, k = idx % 192; h2t[idx] = h2_w[k * 96 + j]; return; }
  idx -= 96 * 192;
  if (idx < 200 * 96) { int j = idx / 96, k = idx % 96; h3t[idx] = h3_w[k * 200 + j]; return; }
}

// ---------------- encoder ----------------
__global__ __launch_bounds__(256) void enc_kernel(
    const float* __restrict__ af, const float* __restrict__ w,
    const float* __restrict__ b, const float* __restrict__ g,
    const float* __restrict__ bb, float* __restrict__ x) {
  const int node = blockIdx.x * 4 + (threadIdx.x >> 6);
  const int lane = threadIdx.x & 63;
  if (node >= NN) return;
  const float a0 = af[node * 4 + 0], a1 = af[node * 4 + 1];
  const float a2 = af[node * 4 + 2], a3 = af[node * 4 + 3];
  float v[3], s = 0.f, ss = 0.f;
#pragma unroll
  for (int i = 0; i < 3; ++i) {
    const int j = lane + i * 64;
    float o = a0 * w[j] + a1 * w[H + j] + a2 * w[2 * H + j] + a3 * w[3 * H + j] + b[j];
    o = gelu(o);
    v[i] = o; s += o; ss += o * o;
  }
#pragma unroll
  for (int m = 1; m < 64; m <<= 1) { s += __shfl_xor(s, m); ss += __shfl_xor(ss, m); }
  const float mu = s * (1.f / H);
  float var = ss * (1.f / H) - mu * mu;
  const float rstd = rsqrtf(fmaxf(var, 0.f) + 1e-5f);
#pragma unroll
  for (int i = 0; i < 3; ++i) {
    const int j = lane + i * 64;
    x[(size_t)node * H + j] = (v[i] - mu) * rstd * g[j] + bb[j];
  }
}

// ---------------- CSR build ----------------
__global__ __launch_bounds__(256) void csr_count(const int* __restrict__ ei,
                                                 int* __restrict__ deg) {
  const int e = blockIdx.x * 256 + threadIdx.x;
  if (e < NE) atomicAdd(&deg[ei[NE + e]], 1);
}

__global__ __launch_bounds__(1024) void csr_scan(const int* __restrict__ deg,
                                                 int* __restrict__ start) {
  __shared__ int wsum[16];
  const int tid = threadIdx.x, lane = tid & 63, wv = tid >> 6;
  int carry = 0;
  for (int base = 0; base < NN; base += 1024) {
    const int i = base + tid;
    int v = (i < NN) ? deg[i] : 0;
    int s = v;
#pragma unroll
    for (int d = 1; d < 64; d <<= 1) {
      int t = __shfl_up(s, d);
      if (lane >= d) s += t;
    }
    if (lane == 63) wsum[wv] = s;
    __syncthreads();
    if (wv == 0) {
      int ws_ = (lane < 16) ? wsum[lane] : 0;
#pragma unroll
      for (int d = 1; d < 16; d <<= 1) {
        int t = __shfl_up(ws_, d);
        if (lane >= d) ws_ += t;
      }
      if (lane < 16) wsum[lane] = ws_;
    }
    __syncthreads();
    const int woff = (wv == 0) ? 0 : wsum[wv - 1];
    if (i < NN) start[i] = carry + woff + s - v;
    carry += wsum[15];
    __syncthreads();
  }
  if (tid == 0) start[NN] = NE;
}

__global__ __launch_bounds__(256) void csr_fill(const int* __restrict__ ei,
                                                const int* __restrict__ start,
                                                int* __restrict__ cur,
                                                int* __restrict__ eidx) {
  const int e = blockIdx.x * 256 + threadIdx.x;
  if (e < NE) {
    const int d = ei[NE + e];
    const int p = start[d] + atomicAdd(&cur[d], 1);
    eidx[p] = e;
  }
}

// ---------------- graph segment boundaries (batch is sorted) ----------------
__global__ __launch_bounds__(256) void gseg_kernel(const int* __restrict__ batch,
                                                   int* __restrict__ gstart,
                                                   int* __restrict__ gend) {
  const int i = blockIdx.x * 256 + threadIdx.x;
  if (i >= NN) return;
  const int b = batch[i];
  if (i == 0 || batch[i - 1] != b) gstart[b] = i;
  if (i == NN - 1 || batch[i + 1] != b) gend[b] = i + 1;
}

// ---------------- fused message MLP, coalesced bf16 output ----------------
// 64 edges/block, 8 waves (512 thr). GEMM1 wave: 64x48. GEMM2 wave: 32x48.
__global__ __launch_bounds__(512, 4) void msg_kernel(
    const float* __restrict__ x, const int* __restrict__ ei,
    const float* __restrict__ ea, const unsigned short* __restrict__ W1t,
    const float* __restrict__ w1last, const float* __restrict__ b1,
    const unsigned short* __restrict__ W2t, const float* __restrict__ b2,
    unsigned short* __restrict__ m) {
  __shared__ unsigned short A[64 * LDA];
  __shared__ float eaS[64];
  const int tid = threadIdx.x;
  const int wave = tid >> 6, lane = tid & 63;
  const int lrow = lane & 15, kgrp = lane >> 4;
  const int tile = blockIdx.x * 64;

  if (tid < 64) eaS[tid] = ea[tile + tid];
  for (int r = wave; r < 64; r += 8) {
    const int e = tile + r;
    const float4* xs4 = (const float4*)(x + (size_t)ei[e] * H);
    const float4* xd4 = (const float4*)(x + (size_t)ei[NE + e] * H);
#pragma unroll
    for (int f = lane; f < 96; f += 64) {
      float4 v = (f < 48) ? xs4[f] : xd4[f - 48];
      *(ushort4*)(&A[r * LDA + f * 4]) =
          make_ushort4(f2bf(v.x), f2bf(v.y), f2bf(v.z), f2bf(v.w));
    }
  }
  __syncthreads();

  // GEMM1: wave owns cols jbase..jbase+47 for all 64 rows
  const int jbase = wave * 48;
  f32x4 acc[4][3];
#pragma unroll
  for (int mf = 0; mf < 4; ++mf)
#pragma unroll
    for (int nf = 0; nf < 3; ++nf)
#pragma unroll
      for (int q = 0; q < 4; ++q) acc[mf][nf][q] = 0.f;

#pragma unroll 2
  for (int kk = 0; kk < 12; ++kk) {
    const int k0 = kk * 32 + kgrp * 8;
    bfrag aF[4];
#pragma unroll
    for (int mf = 0; mf < 4; ++mf)
      aF[mf] = *(const bfrag*)(&A[(lrow + 16 * mf) * LDA + k0]);
#pragma unroll
    for (int nf = 0; nf < 3; ++nf) {
      const bfrag bF = *(const bfrag*)(W1t + (size_t)(jbase + nf * 16 + lrow) * 384 + k0);
#pragma unroll
      for (int mf = 0; mf < 4; ++mf)
        acc[mf][nf] = __builtin_amdgcn_mfma_f32_16x16x32_bf16(aF[mf], bF, acc[mf][nf], 0, 0, 0);
    }
  }
  __syncthreads();  // A reads complete before overwrite

#pragma unroll
  for (int nf = 0; nf < 3; ++nf) {
    const int col = jbase + nf * 16 + lrow;
    const float bias = b1[col], wl = w1last[col];
#pragma unroll
    for (int mf = 0; mf < 4; ++mf) {
#pragma unroll
      for (int q = 0; q < 4; ++q) {
        const int row = 16 * mf + kgrp * 4 + q;
        A[row * LDA + col] = f2bf(gelu(acc[mf][nf][q] + bias + eaS[row] * wl));
      }
    }
  }
  __syncthreads();

  // GEMM2: wave (mh = wave&1, nq = wave>>1): rows mh*32..+31, cols nq*48..+47
  const int mh = wave & 1, j2base = (wave >> 1) * 48;
  f32x4 acc2[2][3];
#pragma unroll
  for (int m2 = 0; m2 < 2; ++m2)
#pragma unroll
    for (int nf = 0; nf < 3; ++nf)
#pragma unroll
      for (int q = 0; q < 4; ++q) acc2[m2][nf][q] = 0.f;

#pragma unroll 2
  for (int kk = 0; kk < 12; ++kk) {
    const int k0 = kk * 32 + kgrp * 8;
    bfrag aF[2];
#pragma unroll
    for (int m2 = 0; m2 < 2; ++m2)
      aF[m2] = *(const bfrag*)(&A[(mh * 32 + m2 * 16 + lrow) * LDA + k0]);
#pragma unroll
    for (int nf = 0; nf < 3; ++nf) {
      const bfrag bF = *(const bfrag*)(W2t + (size_t)(j2base + nf * 16 + lrow) * 384 + k0);
#pragma unroll
      for (int m2 = 0; m2 < 2; ++m2)
        acc2[m2][nf] = __builtin_amdgcn_mfma_f32_16x16x32_bf16(aF[m2], bF, acc2[m2][nf], 0, 0, 0);
    }
  }
#pragma unroll
  for (int nf = 0; nf < 3; ++nf) {
    const int col = j2base + nf * 16 + lrow;
    const float bias = b2[col];
#pragma unroll
    for (int m2 = 0; m2 < 2; ++m2) {
#pragma unroll
      for (int q = 0; q < 4; ++q) {
        const int row = mh * 32 + m2 * 16 + kgrp * 4 + q;
        m[(size_t)(tile + row) * H + col] = f2bf(acc2[m2][nf][q] + bias);
      }
    }
  }
}

// ---------------- update MLP + residual + LN (in-place on x) ----------------
// 64 nodes/block, CSR gather of messages in load phase.
__global__ __launch_bounds__(256, 2) void upd_kernel(
    const unsigned short* __restrict__ Ut, const float* __restrict__ ub,
    const float* __restrict__ lng, const float* __restrict__ lnb,
    const unsigned short* __restrict__ m, const int* __restrict__ start,
    const int* __restrict__ eidx, float* __restrict__ x) {
  __shared__ unsigned short A[64 * LDA];
  const int tid = threadIdx.x;
  const int wave = tid >> 6, lane = tid & 63;
  const int lrow = lane & 15, kgrp = lane >> 4;
  const int tile = blockIdx.x * 64;

  // load: thread t -> row r = t>>2, col-quarter q4 = t&3 (48 cols each half)
  {
    const int r = tid >> 2, q4 = tid & 3;
    const int node = tile + r;
    if (node < NN) {
      const float4* xs = (const float4*)(x + (size_t)node * H + q4 * 48);
#pragma unroll
      for (int i = 0; i < 12; ++i) {
        float4 v = xs[i];
        *(ushort4*)(&A[r * LDA + q4 * 48 + i * 4]) =
            make_ushort4(f2bf(v.x), f2bf(v.y), f2bf(v.z), f2bf(v.w));
      }
      float acc[48];
#pragma unroll
      for (int i = 0; i < 48; ++i) acc[i] = 0.f;
      const int p0 = start[node], p1 = start[node + 1];
      for (int p = p0; p < p1; ++p) {
        const int e = eidx[p];
        const uint4* mr = (const uint4*)(m + (size_t)e * H + q4 * 48);
#pragma unroll
        for (int i = 0; i < 6; ++i) {
          const uint4 u = mr[i];
          acc[i * 8 + 0] += bflo(u.x); acc[i * 8 + 1] += bfhi(u.x);
          acc[i * 8 + 2] += bflo(u.y); acc[i * 8 + 3] += bfhi(u.y);
          acc[i * 8 + 4] += bflo(u.z); acc[i * 8 + 5] += bfhi(u.z);
          acc[i * 8 + 6] += bflo(u.w); acc[i * 8 + 7] += bfhi(u.w);
        }
      }
#pragma unroll
      for (int i = 0; i < 48; i += 4)
        *(ushort4*)(&A[r * LDA + 192 + q4 * 48 + i]) =
            make_ushort4(f2bf(acc[i]), f2bf(acc[i + 1]), f2bf(acc[i + 2]), f2bf(acc[i + 3]));
    } else {
#pragma unroll
      for (int i = 0; i < 48; i += 4) {
        *(ushort4*)(&A[r * LDA + q4 * 48 + i]) = make_ushort4(0, 0, 0, 0);
        *(ushort4*)(&A[r * LDA + 192 + q4 * 48 + i]) = make_ushort4(0, 0, 0, 0);
      }
    }
  }
  __syncthreads();

  f32x4 acc[12];
#pragma unroll
  for (int nf = 0; nf < 12; ++nf)
#pragma unroll
    for (int q = 0; q < 4; ++q) acc[nf][q] = 0.f;

  const int rowb = wave * 16;
#pragma unroll 2
  for (int kk = 0; kk < 12; ++kk) {
    const int k0 = kk * 32 + kgrp * 8;
    const bfrag aF = *(const bfrag*)(&A[(rowb + lrow) * LDA + k0]);
#pragma unroll
    for (int nf = 0; nf < 12; ++nf) {
      const bfrag bF = *(const bfrag*)(Ut + (size_t)(nf * 16 + lrow) * 384 + k0);
      acc[nf] = __builtin_amdgcn_mfma_f32_16x16x32_bf16(aF, bF, acc[nf], 0, 0, 0);
    }
  }

  float s[4] = {0.f, 0.f, 0.f, 0.f}, ss[4] = {0.f, 0.f, 0.f, 0.f};
#pragma unroll
  for (int nf = 0; nf < 12; ++nf) {
    const int col = nf * 16 + lrow;
    const float bias = ub[col];
#pragma unroll
    for (int q = 0; q < 4; ++q) {
      const int node = tile + rowb + kgrp * 4 + q;
      float v = 0.f;
      if (node < NN) v = x[(size_t)node * H + col] + gelu(acc[nf][q] + bias);
      acc[nf][q] = v;
      s[q] += v; ss[q] += v * v;
    }
  }
#pragma unroll
  for (int mm = 1; mm < 16; mm <<= 1) {
#pragma unroll
    for (int q = 0; q < 4; ++q) {
      s[q] += __shfl_xor(s[q], mm);
      ss[q] += __shfl_xor(ss[q], mm);
    }
  }
  float mu[4], rstd[4];
#pragma unroll
  for (int q = 0; q < 4; ++q) {
    mu[q] = s[q] * (1.f / H);
    float var = ss[q] * (1.f / H) - mu[q] * mu[q];
    rstd[q] = rsqrtf(fmaxf(var, 0.f) + 1e-5f);
  }
#pragma unroll
  for (int nf = 0; nf < 12; ++nf) {
    const int col = nf * 16 + lrow;
    const float gg = lng[col], bb = lnb[col];
#pragma unroll
    for (int q = 0; q < 4; ++q) {
      const int node = tile + rowb + kgrp * 4 + q;
      if (node < NN)
        x[(size_t)node * H + col] = (acc[nf][q] - mu[q]) * rstd[q] * gg + bb;
    }
  }
}

// ---------------- pooling (sorted-batch segments) + head MLP ----------------
__global__ __launch_bounds__(256) void head_kernel(
    const float* __restrict__ x, const int* __restrict__ gstart,
    const int* __restrict__ gend,
    const float* __restrict__ h1t, const float* __restrict__ h1b,
    const float* __restrict__ h2t, const float* __restrict__ h2b,
    const float* __restrict__ h3t, const float* __restrict__ h3b,
    float* __restrict__ out) {
  __shared__ float G[4][2 * H];
  __shared__ float Hs[4][H];
  __shared__ float H2s[4][96];
  const int w = threadIdx.x >> 6, lane = threadIdx.x & 63;
  const int gi = blockIdx.x * 4 + w;
  const int ns = gstart[gi], nе = gend[gi];
  float sm[3] = {0.f, 0.f, 0.f};
  float mx[3] = {-INFINITY, -INFINITY, -INFINITY};
  for (int n = ns; n < nе; ++n) {
#pragma unroll
    for (int i = 0; i < 3; ++i) {
      const float v = x[(size_t)n * H + lane + i * 64];
      sm[i] += v; mx[i] = fmaxf(mx[i], v);
    }
  }
  const int cnt = nе - ns;
  const float inv = cnt > 0 ? 1.f / (float)cnt : 0.f;
#pragma unroll
  for (int i = 0; i < 3; ++i) {
    const int j = lane + i * 64;
    G[w][j] = sm[i] * inv;
    G[w][H + j] = mx[i];
  }
  __syncthreads();
#pragma unroll
  for (int i = 0; i < 3; ++i) {
    const int j = lane + i * 64;
    const float4* wr4 = (const float4*)(h1t + (size_t)j * 384);
    float s = h1b[j];
    for (int k4 = 0; k4 < 96; ++k4) {
      float4 ww = wr4[k4];
      s += G[w][k4 * 4 + 0] * ww.x + G[w][k4 * 4 + 1] * ww.y +
           G[w][k4 * 4 + 2] * ww.z + G[w][k4 * 4 + 3] * ww.w;
    }
    Hs[w][j] = gelu(s);
  }
  __syncthreads();
  for (int j = lane; j < 96; j += 64) {
    const float4* wr4 = (const float4*)(h2t + (size_t)j * 192);
    float s = h2b[j];
    for (int k4 = 0; k4 < 48; ++k4) {
      float4 ww = wr4[k4];
      s += Hs[w][k4 * 4 + 0] * ww.x + Hs[w][k4 * 4 + 1] * ww.y +
           Hs[w][k4 * 4 + 2] * ww.z + Hs[w][k4 * 4 + 3] * ww.w;
    }
    H2s[w][j] = gelu(s);
  }
  __syncthreads();
  for (int j = lane; j < 200; j += 64) {
    const float4* wr4 = (const float4*)(h3t + (size_t)j * 96);
    float s = h3b[j];
    for (int k4 = 0; k4 < 24; ++k4) {
      float4 ww = wr4[k4];
      s += H2s[w][k4 * 4 + 0] * ww.x + H2s[w][k4 * 4 + 1] * ww.y +
           H2s[w][k4 * 4 + 2] * ww.z + H2s[w][k4 * 4 + 3] * ww.w;
    }
    out[(size_t)gi * ND + j] = s;
  }
}

extern "C" void kernel_launch(void* const* d_in, const int* in_sizes, int n_in,
                              void* d_out, int out_size, void* d_ws, size_t ws_size,
                              hipStream_t stream) {
  const float* atom   = (const float*)d_in[0];
  const float* ea     = (const float*)d_in[1];
  const int*   ei     = (const int*)d_in[2];
  const int*   batch  = (const int*)d_in[3];
  const float* enc_w  = (const float*)d_in[4];
  const float* enc_b  = (const float*)d_in[5];
  const float* enc_lng= (const float*)d_in[6];
  const float* enc_lnb= (const float*)d_in[7];
  const float* msg_w1 = (const float*)d_in[8];
  const float* msg_b1 = (const float*)d_in[9];
  const float* msg_w2 = (const float*)d_in[10];
  const float* msg_b2 = (const float*)d_in[11];
  const float* upd_w  = (const float*)d_in[12];
  const float* upd_b  = (const float*)d_in[13];
  const float* ln_g   = (const float*)d_in[14];
  const float* ln_b   = (const float*)d_in[15];
  const float* h1_w   = (const float*)d_in[16];
  const float* h1_b   = (const float*)d_in[17];
  const float* h2_w   = (const float*)d_in[18];
  const float* h2_b   = (const float*)d_in[19];
  const float* h3_w   = (const float*)d_in[20];
  const float* h3_b   = (const float*)d_in[21];
  float* out = (float*)d_out;

  char* ws = (char*)d_ws;
  size_t off = 0;
  auto alloc = [&](size_t bytes) -> void* {
    void* p = ws + off;
    off = (off + bytes + 255) & ~(size_t)255;
    return p;
  };
  float* x            = (float*)alloc((size_t)NN * H * 4);
  unsigned short* msg = (unsigned short*)alloc((size_t)NE * H * 2);
  unsigned short* W1t = (unsigned short*)alloc((size_t)NL * 384 * 384 * 2);
  float* w1last       = (float*)alloc((size_t)NL * 384 * 4);
  unsigned short* W2t = (unsigned short*)alloc((size_t)NL * 192 * 384 * 2);
  unsigned short* Ut  = (unsigned short*)alloc((size_t)NL * 192 * 384 * 2);
  float* h1t          = (float*)alloc((size_t)192 * 384 * 4);
  float* h2t          = (float*)alloc((size_t)96 * 192 * 4);
  float* h3t          = (float*)alloc((size_t)200 * 96 * 4);
  int* deg            = (int*)alloc((size_t)NN * 4);
  int* cstart         = (int*)alloc((size_t)(NN + 1) * 4);
  int* eidx           = (int*)alloc((size_t)NE * 4);
  int* gstart         = (int*)alloc((size_t)NG * 4);
  int* gend           = (int*)alloc((size_t)NG * 4);

  prep_kernel<<<6203, 256, 0, stream>>>(msg_w1, msg_w2, upd_w, h1_w, h2_w, h3_w,
                                        W1t, w1last, W2t, Ut, h1t, h2t, h3t);
  enc_kernel<<<NN / 4, 256, 0, stream>>>(atom, enc_w, enc_b, enc_lng, enc_lnb, x);

  // CSR of incoming edges per node
  hipMemsetAsync(deg, 0, (size_t)NN * 4, stream);
  csr_count<<<(NE + 255) / 256, 256, 0, stream>>>(ei, deg);
  csr_scan<<<1, 1024, 0, stream>>>(deg, cstart);
  hipMemsetAsync(deg, 0, (size_t)NN * 4, stream);
  csr_fill<<<(NE + 255) / 256, 256, 0, stream>>>(ei, cstart, deg, eidx);

  // graph segment boundaries
  hipMemsetAsync(gstart, 0, (size_t)NG * 4, stream);
  hipMemsetAsync(gend, 0, (size_t)NG * 4, stream);
  gseg_kernel<<<(NN + 255) / 256, 256, 0, stream>>>(batch, gstart, gend);

  for (int l = 0; l < NL; ++l) {
    msg_kernel<<<NE / 64, 512, 0, stream>>>(
        x, ei, ea, W1t + (size_t)l * 384 * 384, w1last + l * 384,
        msg_b1 + l * 384, W2t + (size_t)l * 192 * 384, msg_b2 + l * 192, msg);
    upd_kernel<<<(NN + 63) / 64, 256, 0, stream>>>(
        Ut + (size_t)l * 192 * 384, upd_b + l * 192, ln_g + l * 192,
        ln_b + l * 192, msg, cstart, eidx, x);
  }
  head_kernel<<<NG / 4, 256, 0, stream>>>(x, gstart, gend, h1t, h1_b, h2t, h2_b,
                                          h3t, h3_b, out);
}

// Round 3
// 1129.993 us; speedup vs baseline: 2.0680x; 1.5133x over previous
//
#include <hip/hip_runtime.h>

#define H 192
#define NL 5
#define NN 60000
#define NE 120000
#define NG 2048
#define ND 200
#define LDA 392  // 384 + 8 bf16 pad -> 784B row stride (16B aligned)

typedef __bf16 bfrag __attribute__((ext_vector_type(8)));
typedef __bf16 bf16x4 __attribute__((ext_vector_type(4)));
typedef float f32x4 __attribute__((ext_vector_type(4)));

__device__ __forceinline__ unsigned short f2bf(float f) {
  union { float f; unsigned u; } v; v.f = f;
  return (unsigned short)((v.u + 0x7FFFu + ((v.u >> 16) & 1u)) >> 16);
}
__device__ __forceinline__ float bflo(unsigned u) {
  union { unsigned u; float f; } v; v.u = u << 16; return v.f;
}
__device__ __forceinline__ float bfhi(unsigned u) {
  union { unsigned u; float f; } v; v.u = u & 0xffff0000u; return v.f;
}
// tanh-approx GELU via exp2; |err| ~3e-4
__device__ __forceinline__ float gelu(float x) {
  const float xt = fminf(fmaxf(x, -8.f), 8.f);
  const float xx = xt * xt;
  const float t = exp2f(xt * (-2.3020922f - 0.10293942f * xx));
  return x * __frcp_rn(1.f + t);
}

// ---------------- weight prep: bf16 + MFMA fragment order ----------------
// Frag layout for a [Jblk][K] weight: idx = ((jblk*12 + kk)*64 + lane)*8 + i
//   j = jblk*16 + (lane&15), k = kk*32 + (lane>>4)*8 + i
__global__ __launch_bounds__(256) void prep_kernel(
    const float* __restrict__ msg_w1, const float* __restrict__ msg_w2,
    const float* __restrict__ upd_w, const float* __restrict__ h1_w,
    const float* __restrict__ h2_w, const float* __restrict__ h3_w,
    unsigned short* __restrict__ W1f, float* __restrict__ w1last,
    unsigned short* __restrict__ W2f, unsigned short* __restrict__ Uf,
    float* __restrict__ h1t, float* __restrict__ h2t, float* __restrict__ h3t) {
  int idx = blockIdx.x * 256 + threadIdx.x;
  const int SW1 = NL * 147456;  // 24 jblk * 12 kk * 512
  const int S2 = NL * 384;
  const int SW2 = NL * 73728;   // 12 jblk * 12 kk * 512
  if (idx < SW1) {
    int l = idx / 147456, r = idx % 147456;
    int i = r & 7, lane = (r >> 3) & 63, t = r >> 9;
    int kk = t % 12, jblk = t / 12;
    int j = jblk * 16 + (lane & 15);
    int k = kk * 32 + ((lane >> 4) << 3) + i;
    W1f[idx] = f2bf(msg_w1[(size_t)l * 385 * 384 + (size_t)k * 384 + j]);
    return;
  }
  idx -= SW1;
  if (idx < S2) {
    int l = idx / 384, j = idx % 384;
    w1last[idx] = msg_w1[(size_t)l * 385 * 384 + 384 * 384 + j];
    return;
  }
  idx -= S2;
  if (idx < SW2) {
    int l = idx / 73728, r = idx % 73728;
    int i = r & 7, lane = (r >> 3) & 63, t = r >> 9;
    int kk = t % 12, jblk = t / 12;
    int j = jblk * 16 + (lane & 15);
    int k = kk * 32 + ((lane >> 4) << 3) + i;
    W2f[idx] = f2bf(msg_w2[(size_t)l * 384 * 192 + (size_t)k * 192 + j]);
    return;
  }
  idx -= SW2;
  if (idx < SW2) {
    int l = idx / 73728, r = idx % 73728;
    int i = r & 7, lane = (r >> 3) & 63, t = r >> 9;
    int kk = t % 12, jblk = t / 12;
    int j = jblk * 16 + (lane & 15);
    int k = kk * 32 + ((lane >> 4) << 3) + i;
    Uf[idx] = f2bf(upd_w[(size_t)l * 384 * 192 + (size_t)k * 192 + j]);
    return;
  }
  idx -= SW2;
  if (idx < 192 * 384) { int j = idx / 384, k = idx % 384; h1t[idx] = h1_w[k * 192 + j]; return; }
  idx -= 192 * 384;
  if (idx < 96 * 192) { int j = idx / 192, k = idx % 192; h2t[idx] = h2_w[k * 96 + j]; return; }
  idx -= 96 * 192;
  if (idx < 200 * 96) { int j = idx / 96, k = idx % 96; h3t[idx] = h3_w[k * 200 + j]; return; }
}

// ---------------- encoder (writes x fp32 and xb bf16) ----------------
__global__ __launch_bounds__(256) void enc_kernel(
    const float* __restrict__ af, const float* __restrict__ w,
    const float* __restrict__ b, const float* __restrict__ g,
    const float* __restrict__ bb, float* __restrict__ x,
    __bf16* __restrict__ xb) {
  const int node = blockIdx.x * 4 + (threadIdx.x >> 6);
  const int lane = threadIdx.x & 63;
  if (node >= NN) return;
  const float a0 = af[node * 4 + 0], a1 = af[node * 4 + 1];
  const float a2 = af[node * 4 + 2], a3 = af[node * 4 + 3];
  float v[3], s = 0.f, ss = 0.f;
#pragma unroll
  for (int i = 0; i < 3; ++i) {
    const int j = lane + i * 64;
    float o = a0 * w[j] + a1 * w[H + j] + a2 * w[2 * H + j] + a3 * w[3 * H + j] + b[j];
    o = gelu(o);
    v[i] = o; s += o; ss += o * o;
  }
#pragma unroll
  for (int m = 1; m < 64; m <<= 1) { s += __shfl_xor(s, m); ss += __shfl_xor(ss, m); }
  const float mu = s * (1.f / H);
  float var = ss * (1.f / H) - mu * mu;
  const float rstd = rsqrtf(fmaxf(var, 0.f) + 1e-5f);
#pragma unroll
  for (int i = 0; i < 3; ++i) {
    const int j = lane + i * 64;
    const float o = (v[i] - mu) * rstd * g[j] + bb[j];
    x[(size_t)node * H + j] = o;
    xb[(size_t)node * H + j] = (__bf16)o;
  }
}

// ---------------- CSR build ----------------
__global__ __launch_bounds__(256) void csr_count(const int* __restrict__ ei,
                                                 int* __restrict__ deg) {
  const int e = blockIdx.x * 256 + threadIdx.x;
  if (e < NE) atomicAdd(&deg[ei[NE + e]], 1);
}

__global__ __launch_bounds__(1024) void csr_scan(const int* __restrict__ deg,
                                                 int* __restrict__ start) {
  __shared__ int wsum[16];
  const int tid = threadIdx.x, lane = tid & 63, wv = tid >> 6;
  int carry = 0;
  for (int base = 0; base < NN; base += 1024) {
    const int i = base + tid;
    int v = (i < NN) ? deg[i] : 0;
    int s = v;
#pragma unroll
    for (int d = 1; d < 64; d <<= 1) {
      int t = __shfl_up(s, d);
      if (lane >= d) s += t;
    }
    if (lane == 63) wsum[wv] = s;
    __syncthreads();
    if (wv == 0) {
      int ws_ = (lane < 16) ? wsum[lane] : 0;
#pragma unroll
      for (int d = 1; d < 16; d <<= 1) {
        int t = __shfl_up(ws_, d);
        if (lane >= d) ws_ += t;
      }
      if (lane < 16) wsum[lane] = ws_;
    }
    __syncthreads();
    const int woff = (wv == 0) ? 0 : wsum[wv - 1];
    if (i < NN) start[i] = carry + woff + s - v;
    carry += wsum[15];
    __syncthreads();
  }
  if (tid == 0) start[NN] = NE;
}

__global__ __launch_bounds__(256) void csr_fill(const int* __restrict__ ei,
                                                const int* __restrict__ start,
                                                int* __restrict__ cur,
                                                int* __restrict__ eidx) {
  const int e = blockIdx.x * 256 + threadIdx.x;
  if (e < NE) {
    const int d = ei[NE + e];
    const int p = start[d] + atomicAdd(&cur[d], 1);
    eidx[p] = e;
  }
}

// ---------------- graph segment boundaries ----------------
__global__ __launch_bounds__(256) void gseg_kernel(const int* __restrict__ batch,
                                                   int* __restrict__ gstart,
                                                   int* __restrict__ gend) {
  const int i = blockIdx.x * 256 + threadIdx.x;
  if (i >= NN) return;
  const int b = batch[i];
  if (i == 0 || batch[i - 1] != b) gstart[b] = i;
  if (i == NN - 1 || batch[i + 1] != b) gend[b] = i + 1;
}

// ---------------- fused message MLP (transposed GEMMs) ----------------
// 64 edges/block, 8 waves. GEMM1-T: hiddenT[j=384][e=64], wave: 96 j x 32 e.
// GEMM2-T: mT[j2=192][e=64], wave: 48 j2 x 32 e. Weights are A-operand
// (fragment-ordered, coalesced); edge tile is B-operand from LDS.
__global__ __launch_bounds__(512, 4) void msg_kernel(
    const __bf16* __restrict__ xb, const int* __restrict__ ei,
    const float* __restrict__ ea, const unsigned short* __restrict__ W1f,
    const float* __restrict__ w1last, const float* __restrict__ b1,
    const unsigned short* __restrict__ W2f, const float* __restrict__ b2,
    unsigned short* __restrict__ m) {
  __shared__ unsigned short A[64 * LDA];
  __shared__ float eaS[64];
  const int tid = threadIdx.x;
  const int wave = tid >> 6, lane = tid & 63;
  const int lrow = lane & 15, kgrp = lane >> 4;
  const int tile = blockIdx.x * 64;

  if (tid < 64) eaS[tid] = ea[tile + tid];
  {
    const int r = tid >> 3, s = tid & 7;
    const int e = tile + r;
    const uint4* ps = (const uint4*)(xb + (size_t)ei[e] * H);
    const uint4* pd = (const uint4*)(xb + (size_t)ei[NE + e] * H);
#pragma unroll
    for (int i = 0; i < 3; ++i)
      *(uint4*)(&A[r * LDA + (s + 8 * i) * 8]) = ps[s + 8 * i];
#pragma unroll
    for (int i = 3; i < 6; ++i)
      *(uint4*)(&A[r * LDA + (s + 8 * i) * 8]) = pd[s + 8 * i - 24];
  }
  __syncthreads();

  const int jb16 = (wave >> 1) * 6;  // 6 j-blocks of 16
  const int eb = (wave & 1) * 32;    // 2 e-blocks of 16
  f32x4 acc[6][2];
#pragma unroll
  for (int mf = 0; mf < 6; ++mf)
#pragma unroll
    for (int nf = 0; nf < 2; ++nf)
#pragma unroll
      for (int q = 0; q < 4; ++q) acc[mf][nf][q] = 0.f;

#pragma unroll 2
  for (int kk = 0; kk < 12; ++kk) {
    const int k0 = kk * 32 + kgrp * 8;
    bfrag bF0 = *(const bfrag*)(&A[(eb + lrow) * LDA + k0]);
    bfrag bF1 = *(const bfrag*)(&A[(eb + 16 + lrow) * LDA + k0]);
#pragma unroll
    for (int mf = 0; mf < 6; ++mf) {
      const bfrag aF = *(const bfrag*)(W1f + ((size_t)((jb16 + mf) * 12 + kk) * 64 + lane) * 8);
      acc[mf][0] = __builtin_amdgcn_mfma_f32_16x16x32_bf16(aF, bF0, acc[mf][0], 0, 0, 0);
      acc[mf][1] = __builtin_amdgcn_mfma_f32_16x16x32_bf16(aF, bF1, acc[mf][1], 0, 0, 0);
    }
  }
  __syncthreads();  // A reads done before overwrite

  // epilogue: lane holds hiddenT[j0..j0+3][e]; write 4 consecutive j -> b64
#pragma unroll
  for (int mf = 0; mf < 6; ++mf) {
    const int j0 = (jb16 + mf) * 16 + kgrp * 4;
    const float bi0 = b1[j0], bi1 = b1[j0 + 1], bi2 = b1[j0 + 2], bi3 = b1[j0 + 3];
    const float wl0 = w1last[j0], wl1 = w1last[j0 + 1], wl2 = w1last[j0 + 2], wl3 = w1last[j0 + 3];
#pragma unroll
    for (int nf = 0; nf < 2; ++nf) {
      const int e = eb + nf * 16 + lrow;
      const float eav = eaS[e];
      bf16x4 v;
      v[0] = (__bf16)gelu(acc[mf][nf][0] + bi0 + eav * wl0);
      v[1] = (__bf16)gelu(acc[mf][nf][1] + bi1 + eav * wl1);
      v[2] = (__bf16)gelu(acc[mf][nf][2] + bi2 + eav * wl2);
      v[3] = (__bf16)gelu(acc[mf][nf][3] + bi3 + eav * wl3);
      *(bf16x4*)(&A[e * LDA + j0]) = v;
    }
  }
  __syncthreads();

  const int j2b = (wave >> 1) * 3;  // 3 j2-blocks of 16
  f32x4 acc2[3][2];
#pragma unroll
  for (int mf = 0; mf < 3; ++mf)
#pragma unroll
    for (int nf = 0; nf < 2; ++nf)
#pragma unroll
      for (int q = 0; q < 4; ++q) acc2[mf][nf][q] = 0.f;

#pragma unroll 2
  for (int kk = 0; kk < 12; ++kk) {
    const int k0 = kk * 32 + kgrp * 8;
    bfrag bF0 = *(const bfrag*)(&A[(eb + lrow) * LDA + k0]);
    bfrag bF1 = *(const bfrag*)(&A[(eb + 16 + lrow) * LDA + k0]);
#pragma unroll
    for (int mf = 0; mf < 3; ++mf) {
      const bfrag aF = *(const bfrag*)(W2f + ((size_t)((j2b + mf) * 12 + kk) * 64 + lane) * 8);
      acc2[mf][0] = __builtin_amdgcn_mfma_f32_16x16x32_bf16(aF, bF0, acc2[mf][0], 0, 0, 0);
      acc2[mf][1] = __builtin_amdgcn_mfma_f32_16x16x32_bf16(aF, bF1, acc2[mf][1], 0, 0, 0);
    }
  }
#pragma unroll
  for (int mf = 0; mf < 3; ++mf) {
    const int j0 = (j2b + mf) * 16 + kgrp * 4;
    const float bi0 = b2[j0], bi1 = b2[j0 + 1], bi2 = b2[j0 + 2], bi3 = b2[j0 + 3];
#pragma unroll
    for (int nf = 0; nf < 2; ++nf) {
      const int e = eb + nf * 16 + lrow;
      bf16x4 v;
      v[0] = (__bf16)(acc2[mf][nf][0] + bi0);
      v[1] = (__bf16)(acc2[mf][nf][1] + bi1);
      v[2] = (__bf16)(acc2[mf][nf][2] + bi2);
      v[3] = (__bf16)(acc2[mf][nf][3] + bi3);
      *(bf16x4*)(m + (size_t)(tile + e) * H + j0) = v;
    }
  }
}

// ---------------- update MLP + residual + LN ----------------
__global__ __launch_bounds__(256, 2) void upd_kernel(
    const unsigned short* __restrict__ Uf, const float* __restrict__ ub,
    const float* __restrict__ lng, const float* __restrict__ lnb,
    const unsigned short* __restrict__ m, const int* __restrict__ start,
    const int* __restrict__ eidx, float* __restrict__ x,
    __bf16* __restrict__ xb) {
  __shared__ unsigned short A[64 * LDA];
  const int tid = threadIdx.x;
  const int wave = tid >> 6, lane = tid & 63;
  const int lrow = lane & 15, kgrp = lane >> 4;
  const int tile = blockIdx.x * 64;

  {
    const int r = tid >> 2, q4 = tid & 3;
    const int node = tile + r;
    if (node < NN) {
      const uint4* px = (const uint4*)(xb + (size_t)node * H + q4 * 48);
#pragma unroll
      for (int i = 0; i < 6; ++i)
        *(uint4*)(&A[r * LDA + q4 * 48 + i * 8]) = px[i];
      float acc[48];
#pragma unroll
      for (int i = 0; i < 48; ++i) acc[i] = 0.f;
      const int p0 = start[node], p1 = start[node + 1];
      for (int p = p0; p < p1; ++p) {
        const int e = eidx[p];
        const uint4* mr = (const uint4*)(m + (size_t)e * H + q4 * 48);
#pragma unroll
        for (int i = 0; i < 6; ++i) {
          const uint4 u = mr[i];
          acc[i * 8 + 0] += bflo(u.x); acc[i * 8 + 1] += bfhi(u.x);
          acc[i * 8 + 2] += bflo(u.y); acc[i * 8 + 3] += bfhi(u.y);
          acc[i * 8 + 4] += bflo(u.z); acc[i * 8 + 5] += bfhi(u.z);
          acc[i * 8 + 6] += bflo(u.w); acc[i * 8 + 7] += bfhi(u.w);
        }
      }
#pragma unroll
      for (int i = 0; i < 48; i += 4) {
        bf16x4 v;
        v[0] = (__bf16)acc[i]; v[1] = (__bf16)acc[i + 1];
        v[2] = (__bf16)acc[i + 2]; v[3] = (__bf16)acc[i + 3];
        *(bf16x4*)(&A[r * LDA + 192 + q4 * 48 + i]) = v;
      }
    } else {
#pragma unroll
      for (int i = 0; i < 48; i += 8) {
        *(uint4*)(&A[r * LDA + q4 * 48 + i]) = make_uint4(0, 0, 0, 0);
        *(uint4*)(&A[r * LDA + 192 + q4 * 48 + i]) = make_uint4(0, 0, 0, 0);
      }
    }
  }
  __syncthreads();

  f32x4 acc[12];
#pragma unroll
  for (int nf = 0; nf < 12; ++nf)
#pragma unroll
    for (int q = 0; q < 4; ++q) acc[nf][q] = 0.f;

  const int rowb = wave * 16;
#pragma unroll 2
  for (int kk = 0; kk < 12; ++kk) {
    const int k0 = kk * 32 + kgrp * 8;
    const bfrag aF = *(const bfrag*)(&A[(rowb + lrow) * LDA + k0]);
#pragma unroll
    for (int nf = 0; nf < 12; ++nf) {
      const bfrag bF = *(const bfrag*)(Uf + ((size_t)(nf * 12 + kk) * 64 + lane) * 8);
      acc[nf] = __builtin_amdgcn_mfma_f32_16x16x32_bf16(aF, bF, acc[nf], 0, 0, 0);
    }
  }

  float s[4] = {0.f, 0.f, 0.f, 0.f}, ss[4] = {0.f, 0.f, 0.f, 0.f};
#pragma unroll
  for (int nf = 0; nf < 12; ++nf) {
    const int col = nf * 16 + lrow;
    const float bias = ub[col];
#pragma unroll
    for (int q = 0; q < 4; ++q) {
      const int node = tile + rowb + kgrp * 4 + q;
      float v = 0.f;
      if (node < NN) v = x[(size_t)node * H + col] + gelu(acc[nf][q] + bias);
      acc[nf][q] = v;
      s[q] += v; ss[q] += v * v;
    }
  }
#pragma unroll
  for (int mm = 1; mm < 16; mm <<= 1) {
#pragma unroll
    for (int q = 0; q < 4; ++q) {
      s[q] += __shfl_xor(s[q], mm);
      ss[q] += __shfl_xor(ss[q], mm);
    }
  }
  float mu[4], rstd[4];
#pragma unroll
  for (int q = 0; q < 4; ++q) {
    mu[q] = s[q] * (1.f / H);
    float var = ss[q] * (1.f / H) - mu[q] * mu[q];
    rstd[q] = rsqrtf(fmaxf(var, 0.f) + 1e-5f);
  }
#pragma unroll
  for (int nf = 0; nf < 12; ++nf) {
    const int col = nf * 16 + lrow;
    const float gg = lng[col], bb = lnb[col];
#pragma unroll
    for (int q = 0; q < 4; ++q) {
      const int node = tile + rowb + kgrp * 4 + q;
      if (node < NN) {
        const float o = (acc[nf][q] - mu[q]) * rstd[q] * gg + bb;
        x[(size_t)node * H + col] = o;
        xb[(size_t)node * H + col] = (__bf16)o;
      }
    }
  }
}

// ---------------- pooling + head MLP ----------------
__global__ __launch_bounds__(256) void head_kernel(
    const float* __restrict__ x, const int* __restrict__ gstart,
    const int* __restrict__ gend,
    const float* __restrict__ h1t, const float* __restrict__ h1b,
    const float* __restrict__ h2t, const float* __restrict__ h2b,
    const float* __restrict__ h3t, const float* __restrict__ h3b,
    float* __restrict__ out) {
  __shared__ float G[4][2 * H];
  __shared__ float Hs[4][H];
  __shared__ float H2s[4][96];
  const int w = threadIdx.x >> 6, lane = threadIdx.x & 63;
  const int gi = blockIdx.x * 4 + w;
  const int n0 = gstart[gi], n1 = gend[gi];
  float sm[3] = {0.f, 0.f, 0.f};
  float mx[3] = {-INFINITY, -INFINITY, -INFINITY};
  for (int n = n0; n < n1; ++n) {
#pragma unroll
    for (int i = 0; i < 3; ++i) {
      const float v = x[(size_t)n * H + lane + i * 64];
      sm[i] += v; mx[i] = fmaxf(mx[i], v);
    }
  }
  const int cnt = n1 - n0;
  const float inv = cnt > 0 ? 1.f / (float)cnt : 0.f;
#pragma unroll
  for (int i = 0; i < 3; ++i) {
    const int j = lane + i * 64;
    G[w][j] = sm[i] * inv;
    G[w][H + j] = mx[i];
  }
  __syncthreads();
#pragma unroll
  for (int i = 0; i < 3; ++i) {
    const int j = lane + i * 64;
    const float4* wr4 = (const float4*)(h1t + (size_t)j * 384);
    float s = h1b[j];
    for (int k4 = 0; k4 < 96; ++k4) {
      float4 ww = wr4[k4];
      s += G[w][k4 * 4 + 0] * ww.x + G[w][k4 * 4 + 1] * ww.y +
           G[w][k4 * 4 + 2] * ww.z + G[w][k4 * 4 + 3] * ww.w;
    }
    Hs[w][j] = gelu(s);
  }
  __syncthreads();
  for (int j = lane; j < 96; j += 64) {
    const float4* wr4 = (const float4*)(h2t + (size_t)j * 192);
    float s = h2b[j];
    for (int k4 = 0; k4 < 48; ++k4) {
      float4 ww = wr4[k4];
      s += Hs[w][k4 * 4 + 0] * ww.x + Hs[w][k4 * 4 + 1] * ww.y +
           Hs[w][k4 * 4 + 2] * ww.z + Hs[w][k4 * 4 + 3] * ww.w;
    }
    H2s[w][j] = gelu(s);
  }
  __syncthreads();
  for (int j = lane; j < 200; j += 64) {
    const float4* wr4 = (const float4*)(h3t + (size_t)j * 96);
    float s = h3b[j];
    for (int k4 = 0; k4 < 24; ++k4) {
      float4 ww = wr4[k4];
      s += H2s[w][k4 * 4 + 0] * ww.x + H2s[w][k4 * 4 + 1] * ww.y +
           H2s[w][k4 * 4 + 2] * ww.z + H2s[w][k4 * 4 + 3] * ww.w;
    }
    out[(size_t)gi * ND + j] = s;
  }
}

extern "C" void kernel_launch(void* const* d_in, const int* in_sizes, int n_in,
                              void* d_out, int out_size, void* d_ws, size_t ws_size,
                              hipStream_t stream) {
  const float* atom   = (const float*)d_in[0];
  const float* ea     = (const float*)d_in[1];
  const int*   ei     = (const int*)d_in[2];
  const int*   batch  = (const int*)d_in[3];
  const float* enc_w  = (const float*)d_in[4];
  const float* enc_b  = (const float*)d_in[5];
  const float* enc_lng= (const float*)d_in[6];
  const float* enc_lnb= (const float*)d_in[7];
  const float* msg_w1 = (const float*)d_in[8];
  const float* msg_b1 = (const float*)d_in[9];
  const float* msg_w2 = (const float*)d_in[10];
  const float* msg_b2 = (const float*)d_in[11];
  const float* upd_w  = (const float*)d_in[12];
  const float* upd_b  = (const float*)d_in[13];
  const float* ln_g   = (const float*)d_in[14];
  const float* ln_b   = (const float*)d_in[15];
  const float* h1_w   = (const float*)d_in[16];
  const float* h1_b   = (const float*)d_in[17];
  const float* h2_w   = (const float*)d_in[18];
  const float* h2_b   = (const float*)d_in[19];
  const float* h3_w   = (const float*)d_in[20];
  const float* h3_b   = (const float*)d_in[21];
  float* out = (float*)d_out;

  char* ws = (char*)d_ws;
  size_t off = 0;
  auto alloc = [&](size_t bytes) -> void* {
    void* p = ws + off;
    off = (off + bytes + 255) & ~(size_t)255;
    return p;
  };
  float* x            = (float*)alloc((size_t)NN * H * 4);
  __bf16* xb          = (__bf16*)alloc((size_t)NN * H * 2);
  unsigned short* msg = (unsigned short*)alloc((size_t)NE * H * 2);
  unsigned short* W1f = (unsigned short*)alloc((size_t)NL * 147456 * 2);
  float* w1last       = (float*)alloc((size_t)NL * 384 * 4);
  unsigned short* W2f = (unsigned short*)alloc((size_t)NL * 73728 * 2);
  unsigned short* Uf  = (unsigned short*)alloc((size_t)NL * 73728 * 2);
  float* h1t          = (float*)alloc((size_t)192 * 384 * 4);
  float* h2t          = (float*)alloc((size_t)96 * 192 * 4);
  float* h3t          = (float*)alloc((size_t)200 * 96 * 4);
  int* deg            = (int*)alloc((size_t)NN * 4);
  int* cstart         = (int*)alloc((size_t)(NN + 1) * 4);
  int* eidx           = (int*)alloc((size_t)NE * 4);
  int* gstart         = (int*)alloc((size_t)NG * 4);
  int* gend           = (int*)alloc((size_t)NG * 4);

  prep_kernel<<<6203, 256, 0, stream>>>(msg_w1, msg_w2, upd_w, h1_w, h2_w, h3_w,
                                        W1f, w1last, W2f, Uf, h1t, h2t, h3t);
  enc_kernel<<<NN / 4, 256, 0, stream>>>(atom, enc_w, enc_b, enc_lng, enc_lnb, x, xb);

  hipMemsetAsync(deg, 0, (size_t)NN * 4, stream);
  csr_count<<<(NE + 255) / 256, 256, 0, stream>>>(ei, deg);
  csr_scan<<<1, 1024, 0, stream>>>(deg, cstart);
  hipMemsetAsync(deg, 0, (size_t)NN * 4, stream);
  csr_fill<<<(NE + 255) / 256, 256, 0, stream>>>(ei, cstart, deg, eidx);

  hipMemsetAsync(gstart, 0, (size_t)NG * 4, stream);
  hipMemsetAsync(gend, 0, (size_t)NG * 4, stream);
  gseg_kernel<<<(NN + 255) / 256, 256, 0, stream>>>(batch, gstart, gend);

  for (int l = 0; l < NL; ++l) {
    msg_kernel<<<NE / 64, 512, 0, stream>>>(
        xb, ei, ea, W1f + (size_t)l * 147456, w1last + l * 384,
        msg_b1 + l * 384, W2f + (size_t)l * 73728, msg_b2 + l * 192, msg);
    upd_kernel<<<(NN + 63) / 64, 256, 0, stream>>>(
        Uf + (size_t)l * 73728, upd_b + l * 192, ln_g + l * 192,
        ln_b + l * 192, msg, cstart, eidx, x, xb);
  }
  head_kernel<<<NG / 4, 256, 0, stream>>>(x, gstart, gend, h1t, h1_b, h2t, h2_b,
                                          h3t, h3_b, out);
}